// Round 11
// baseline (203.445 us; speedup 1.0000x reference)
//
#include <hip/hip_runtime.h>

#define NN 50000
#define DD 128
#define SLOPE 0.01f
#define NB 782        // buckets of 64 nodes: bucket = v>>6
#define BCAP 2304     // per-bucket cap; mean 2046, sigma 45 -> +5.7 sigma (+ovf net)
#define NSB 49        // super-buckets of 1024 nodes: sb = v>>10
#define SBW 1024
#define SCAP 34816    // per-super cap; mean 32768, sigma 179 -> +11 sigma
#define ECH1 4096     // edges per level-1 chunk (391 chunks)
#define RSL 2048      // records per rebin slice
#define RS 17         // slices per super (17*2048 = 34816 = SCAP)
#define OVCAP 8192
#define HP 136        // Hs row pitch (bf16) in the fused-fallback kernel
#define GCHUNK 196    // XCD swizzle chunk: ceil(NB*2/8); grid pad 8*196=1568

using bf16x8 = __attribute__((ext_vector_type(8))) short;
using f32x4  = __attribute__((ext_vector_type(4))) float;

// ---------------- bf16 helpers (RNE) ----------------
__device__ inline float bflo(unsigned int w) { return __uint_as_float(w << 16); }
__device__ inline float bfhi(unsigned int w) { return __uint_as_float(w & 0xffff0000u); }
__device__ inline float sbf(short s) {
    return __uint_as_float(((unsigned int)(unsigned short)s) << 16);
}
__device__ inline unsigned int rnebf(float f) {
    unsigned int u = __float_as_uint(f);
    return (u + 0x7fffu + ((u >> 16) & 1u)) >> 16;
}
__device__ inline unsigned int pack2(float lo, float hi) {
    return rnebf(lo) | (rnebf(hi) << 16);
}
__device__ inline void addrow(float* acc, uint4 r) {
    acc[0] += bflo(r.x); acc[1] += bfhi(r.x);
    acc[2] += bflo(r.y); acc[3] += bfhi(r.y);
    acc[4] += bflo(r.z); acc[5] += bfhi(r.z);
    acc[6] += bflo(r.w); acc[7] += bfhi(r.w);
}

// ROW-MAJOR Ebf (r6 lesson: column planes halve line efficiency).
__device__ inline void convert_item(
    const float* __restrict__ E, const float* __restrict__ W1,
    const float* __restrict__ W2, unsigned short* __restrict__ Ebf,
    unsigned short* __restrict__ W1b, unsigned short* __restrict__ W2b, int t)
{
    const int NE8 = NN * DD / 8;      // 800000
    const int NW8 = DD * DD / 8;      // 2048
    const float* s; unsigned short* d; int idx;
    if (t < NE8)                { s = E;  d = Ebf; idx = t; }
    else if (t < NE8 + NW8)     { s = W1; d = W1b; idx = t - NE8; }
    else if (t < NE8 + 2 * NW8) { s = W2; d = W2b; idx = t - NE8 - NW8; }
    else return;
    float4 a = ((const float4*)s)[(size_t)idx * 2];
    float4 b = ((const float4*)s)[(size_t)idx * 2 + 1];
    uint4 o;
    o.x = pack2(a.x, a.y); o.y = pack2(a.z, a.w);
    o.z = pack2(b.x, b.y); o.w = pack2(b.z, b.w);
    ((uint4*)d)[idx] = o;
}

// ---------------------------------------------------------------------------
// Level-1 binning + convert (r7 verbatim -- binning frozen this round).
// Record: u (bits 0..15) | v&1023 (bits 16..25).
// ---------------------------------------------------------------------------
__global__ __launch_bounds__(512) void scatter_convert(
    const float* __restrict__ E, const float* __restrict__ W1,
    const float* __restrict__ W2, const int* __restrict__ src,
    const int* __restrict__ dst, unsigned short* __restrict__ Ebf,
    unsigned short* __restrict__ W1b, unsigned short* __restrict__ W2b,
    int* __restrict__ gtail1, unsigned int* __restrict__ stag1,
    int* __restrict__ ovf_cnt, int2* __restrict__ ovf,
    int n_edges, int nch1)
{
    const int tid = threadIdx.x;
    if (blockIdx.x >= nch1) {
        convert_item(E, W1, W2, Ebf, W1b, W2b,
                     (blockIdx.x - nch1) * 512 + tid);
        return;
    }

    __shared__ int cnt49[NSB];
    const int e0 = blockIdx.x * ECH1;
    int vv[8], uu[8];

    if (tid < NSB) cnt49[tid] = 0;
    __syncthreads();
    #pragma unroll
    for (int k = 0; k < 8; ++k) {
        int idx = e0 + tid + k * 512;
        if (idx < n_edges) {
            vv[k] = dst[idx]; uu[k] = src[idx];
            atomicAdd(&cnt49[vv[k] >> 10], 1);
        } else vv[k] = -1;
    }
    __syncthreads();
    if (tid < NSB) {
        int c = cnt49[tid];
        cnt49[tid] = c ? atomicAdd(&gtail1[tid], c) : 0;  // -> running pos
    }
    __syncthreads();
    #pragma unroll
    for (int k = 0; k < 8; ++k) {
        if (vv[k] < 0) continue;
        int sb = vv[k] >> 10;
        int p = atomicAdd(&cnt49[sb], 1);
        if (p < SCAP) {
            stag1[(size_t)sb * SCAP + p] =
                (unsigned int)uu[k] | ((unsigned int)(vv[k] & 1023) << 16);
        } else {
            int oi = atomicAdd(ovf_cnt, 1);
            if (oi < OVCAP) ovf[oi] = make_int2(uu[k], vv[k]);
        }
    }
}

// ---------------------------------------------------------------------------
// Level-2 rebin (r7 verbatim).
// ---------------------------------------------------------------------------
__global__ __launch_bounds__(256) void rebin(
    const int* __restrict__ gtail1, const unsigned int* __restrict__ stag1,
    int* __restrict__ gtail, unsigned int* __restrict__ stag,
    int* __restrict__ ovf_cnt, int2* __restrict__ ovf)
{
    const int sb = blockIdx.x / RS, sl = blockIdx.x % RS;
    const int tid = threadIdx.x;
    int len = gtail1[sb]; len = len < SCAP ? len : SCAP;
    const int i0 = sl * RSL;
    const int i1 = min(i0 + RSL, len);

    __shared__ int cnt16[16], pos16[16];
    if (tid < 16) cnt16[tid] = 0;
    __syncthreads();

    unsigned int r[8];
    const unsigned int* seg = stag1 + (size_t)sb * SCAP;
    #pragma unroll
    for (int k = 0; k < 8; ++k) {
        int idx = i0 + tid + k * 256;
        if (idx < i1) {
            r[k] = seg[idx];
            atomicAdd(&cnt16[(r[k] >> 22) & 15], 1);
        } else r[k] = 0xffffffffu;
    }
    __syncthreads();
    if (tid < 16) {
        int c = cnt16[tid];
        int bb = sb * 16 + tid;
        pos16[tid] = (c && bb < NB) ? atomicAdd(&gtail[bb], c) : 0;
    }
    __syncthreads();
    #pragma unroll
    for (int k = 0; k < 8; ++k) {
        if (r[k] == 0xffffffffu) continue;
        int j = (r[k] >> 22) & 15;
        int p = atomicAdd(&pos16[j], 1);
        int bb = sb * 16 + j;
        if (p < BCAP) {
            stag[(size_t)bb * BCAP + p] = r[k] & 0x3fffffu;
        } else {
            int oi = atomicAdd(ovf_cnt, 1);
            if (oi < OVCAP)
                ovf[oi] = make_int2((int)(r[k] & 0xffffu),
                                    sb * SBW + (int)((r[k] >> 16) & 1023));
        }
    }
}

// ---------------------------------------------------------------------------
// bucket_gather (r10 proven 43.6us, FETCH 90MB) + XCD CO-LOCATION SWIZZLE:
// default dispatch round-robins consecutive blocks across 8 XCDs, so the
// two halves (2b,2b+1) of a bucket fetch the SAME Ebf lines into TWO
// different L2s. Swizzle logical=(bid&7)*GCHUNK+(bid>>3) puts pairs +
// neighbor buckets on one XCD -> L2 fill shared. Grid padded to 1568.
// ---------------------------------------------------------------------------
__global__ __launch_bounds__(256, 4) void bucket_gather(
    const unsigned short* __restrict__ Ebf, const int* __restrict__ gtail,
    const unsigned int* __restrict__ stag, const int* __restrict__ ovf_cnt,
    const int2* __restrict__ ovf, float* __restrict__ Hf)
{
    __shared__ unsigned short sorted[BCAP];   // 4.6 KB
    __shared__ int cnt1k[1024];               // counts -> placement pos
    __shared__ int bstart[1025];              // bin exclusive bases
    __shared__ int wsum[4];
    __shared__ int s_novf;

    const int logical = (blockIdx.x & 7) * GCHUNK + (blockIdx.x >> 3);
    if (logical >= NB * 2) return;
    const int b = logical >> 1;
    const int h = logical & 1;
    const int tid = threadIdx.x;
    int len = gtail[b]; len = len < BCAP ? len : BCAP;
    const unsigned int* seg = stag + (size_t)b * BCAP;

    if (tid == 0) { int t = *ovf_cnt; s_novf = t < OVCAP ? t : OVCAP; }
    #pragma unroll
    for (int j = 0; j < 4; ++j) cnt1k[tid * 4 + j] = 0;
    __syncthreads();
    for (int i = tid; i < len; i += 256) {
        unsigned int r = seg[i];
        int key = (int)(((r >> 16) & 63) << 4) | (int)((r & 0xffffu) >> 12);
        atomicAdd(&cnt1k[key], 1);
    }
    __syncthreads();
    // exclusive scan of 1024 counters: 4 per thread + wave scan + wave bases
    {
        const int lane = tid & 63, w = tid >> 6;
        int c[4], loc[4]; int s = 0;
        #pragma unroll
        for (int j = 0; j < 4; ++j) {
            c[j] = cnt1k[tid * 4 + j]; loc[j] = s; s += c[j];
        }
        int incl = s;
        #pragma unroll
        for (int d = 1; d < 64; d <<= 1) {
            int t2 = __shfl_up(incl, d);
            if (lane >= d) incl += t2;
        }
        if (lane == 63) wsum[w] = incl;
        __syncthreads();
        int wbase = 0;
        for (int w2 = 0; w2 < w; ++w2) wbase += wsum[w2];
        int base = wbase + incl - s;
        #pragma unroll
        for (int j = 0; j < 4; ++j) {
            bstart[tid * 4 + j] = base + loc[j];
            cnt1k[tid * 4 + j]  = base + loc[j];   // becomes pos
        }
        if (tid == 255) bstart[1024] = base + s;   // == len
    }
    __syncthreads();
    for (int i = tid; i < len; i += 256) {
        unsigned int r = seg[i];
        int key = (int)(((r >> 16) & 63) << 4) | (int)((r & 0xffffu) >> 12);
        int p = atomicAdd(&cnt1k[key], 1);
        sorted[p] = (unsigned short)(r & 0xffffu);
    }
    __syncthreads();
    const int novf = s_novf;

    // ---- gather: 8 lanes per node (one 128B line), 32 nodes/pass, 2 passes
    const int g = tid >> 3;
    const int c = tid & 7;
    const uint4* E4 = (const uint4*)Ebf;
    for (int p2 = 0; p2 < 2; ++p2) {
        int nl = p2 * 32 + g;
        int v = b * 64 + nl;
        if (v >= NN) continue;
        float acc[8] = {};
        int i = bstart[nl << 4], e1 = bstart[(nl + 1) << 4];
        uint4 r[8];
        for (; i + 8 <= e1; i += 8) {
            #pragma unroll
            for (int k = 0; k < 8; ++k)
                r[k] = E4[(size_t)sorted[i + k] * 16 + h * 8 + c];
            __builtin_amdgcn_sched_barrier(0);
            #pragma unroll
            for (int k = 0; k < 8; ++k) addrow(acc, r[k]);
        }
        for (; i + 2 <= e1; i += 2) {
            uint4 r0 = E4[(size_t)sorted[i]     * 16 + h * 8 + c];
            uint4 r1 = E4[(size_t)sorted[i + 1] * 16 + h * 8 + c];
            addrow(acc, r0); addrow(acc, r1);
        }
        if (i < e1) addrow(acc, E4[(size_t)sorted[i] * 16 + h * 8 + c]);

        if (novf > 0) {                    // rare path: fold overflow edges
            for (int k = 0; k < novf; ++k) {
                int2 e = ovf[k];
                if (e.y == v) addrow(acc, E4[(size_t)e.x * 16 + h * 8 + c]);
            }
        }
        float* o = Hf + (size_t)v * DD + h * 64 + c * 8;
        *(float4*)o       = make_float4(acc[0], acc[1], acc[2], acc[3]);
        *(float4*)(o + 4) = make_float4(acc[4], acc[5], acc[6], acc[7]);
    }
}

// ---------------------------------------------------------------------------
// bucket_gemm, COLUMN-HALF SPLIT (gemm had the same grid-starvation as the
// old gather: 782 blocks = 12 waves/CU streaming 64 MB). Grid NB*2 padded
// to 1568 with the SAME XCD swizzle -- block (b,h): wave w does rows
// b*64+w*16, output cols h*64..h*64+63. aH/aE full-K loads are duplicated
// across h but L2-hot on the shared XCD. 24 waves/CU.
// ---------------------------------------------------------------------------
__global__ __launch_bounds__(256) void bucket_gemm(
    const float* __restrict__ Hf, const unsigned short* __restrict__ Ebf,
    const unsigned short* __restrict__ W1b, const unsigned short* __restrict__ W2b,
    const float* __restrict__ b1, const float* __restrict__ b2,
    float* __restrict__ out)
{
    const int logical = (blockIdx.x & 7) * GCHUNK + (blockIdx.x >> 3);
    if (logical >= NB * 2) return;
    const int b = logical >> 1;
    const int h = logical & 1;
    const int tid = threadIdx.x;
    const int wave = tid >> 6;
    const int lane = tid & 63;
    const int v0 = b * 64 + wave * 16;
    if (v0 >= NN) return;
    const int m = lane & 15;
    const int quad = lane >> 4;

    bf16x8 aH[4], aE[4];
    const float* hrow = Hf + (size_t)(v0 + m) * DD + quad * 8;
    const unsigned short* erow = Ebf + (size_t)(v0 + m) * DD + quad * 8;
    #pragma unroll
    for (int ks = 0; ks < 4; ++ks) {
        float4 f0 = *(const float4*)(hrow + ks * 32);
        float4 f1 = *(const float4*)(hrow + ks * 32 + 4);
        bf16x8 e8 = *(const bf16x8*)(erow + ks * 32);
        bf16x8 h8, eh;
        h8[0] = (short)rnebf(f0.x); h8[1] = (short)rnebf(f0.y);
        h8[2] = (short)rnebf(f0.z); h8[3] = (short)rnebf(f0.w);
        h8[4] = (short)rnebf(f1.x); h8[5] = (short)rnebf(f1.y);
        h8[6] = (short)rnebf(f1.z); h8[7] = (short)rnebf(f1.w);
        #pragma unroll
        for (int j = 0; j < 8; ++j)
            eh[j] = (short)rnebf(sbf(h8[j]) * sbf(e8[j]));
        aH[ks] = h8; aE[ks] = eh;
    }

    #pragma unroll
    for (int jt = 0; jt < 4; ++jt) {
        const int j0 = h * 64 + jt * 16;
        const unsigned short* w1r = W1b + (size_t)(j0 + m) * DD + quad * 8;
        const unsigned short* w2r = W2b + (size_t)(j0 + m) * DD + quad * 8;
        f32x4 acc1 = {0.f, 0.f, 0.f, 0.f}, acc2 = {0.f, 0.f, 0.f, 0.f};
        #pragma unroll
        for (int ks = 0; ks < 4; ++ks) {
            bf16x8 bw1 = *(const bf16x8*)(w1r + ks * 32);
            bf16x8 bw2 = *(const bf16x8*)(w2r + ks * 32);
            acc1 = __builtin_amdgcn_mfma_f32_16x16x32_bf16(aH[ks], bw1, acc1, 0, 0, 0);
            acc2 = __builtin_amdgcn_mfma_f32_16x16x32_bf16(aE[ks], bw2, acc2, 0, 0, 0);
        }
        const float bb1 = b1[j0 + m], bb2 = b2[j0 + m];
        #pragma unroll
        for (int i = 0; i < 4; ++i) {
            int row = v0 + quad * 4 + i;
            if (row < NN) {
                float x1 = acc1[i] + bb1; x1 = x1 > 0.f ? x1 : SLOPE * x1;
                float x2 = acc2[i] + bb2; x2 = x2 > 0.f ? x2 : SLOPE * x2;
                out[(size_t)row * DD + j0 + m] = x1 + x2;
            }
        }
    }
}

// ---------------------------------------------------------------------------
// Fused fallback (r7 verbatim, used when ws can't hold Hf): 84-85 us proven.
// ---------------------------------------------------------------------------
__global__ __launch_bounds__(256, 4) void bucket_fused(
    const unsigned short* __restrict__ Ebf, const int* __restrict__ gtail,
    const unsigned int* __restrict__ stag, const int* __restrict__ ovf_cnt,
    const int2* __restrict__ ovf,
    const unsigned short* __restrict__ W1b, const unsigned short* __restrict__ W2b,
    const float* __restrict__ b1, const float* __restrict__ b2,
    float* __restrict__ out)
{
    __shared__ unsigned short sorted[BCAP];
    __shared__ unsigned short Hs[64][HP];
    __shared__ int cnt[64], off[65], pos[64];
    __shared__ int s_novf;

    const int b = blockIdx.x;
    const int tid = threadIdx.x;
    int len = gtail[b]; len = len < BCAP ? len : BCAP;
    const unsigned int* seg = stag + (size_t)b * BCAP;

    if (tid == 0) { int t = *ovf_cnt; s_novf = t < OVCAP ? t : OVCAP; }
    if (tid < 64) cnt[tid] = 0;
    __syncthreads();
    for (int i = tid; i < len; i += 256)
        atomicAdd(&cnt[(seg[i] >> 16) & 63], 1);
    __syncthreads();
    if (tid < 64) {
        int cv = cnt[tid];
        int incl = cv;
        #pragma unroll
        for (int d = 1; d < 64; d <<= 1) {
            int t2 = __shfl_up(incl, d);
            if (tid >= d) incl += t2;
        }
        off[tid] = incl - cv;
        pos[tid] = incl - cv;
        if (tid == 63) off[64] = incl;
    }
    __syncthreads();
    for (int i = tid; i < len; i += 256) {
        unsigned int r = seg[i];
        int p = atomicAdd(&pos[(r >> 16) & 63], 1);
        sorted[p] = (unsigned short)(r & 0xffffu);
    }
    __syncthreads();
    const int novf = s_novf;

    const int g = tid >> 4;
    const int c = tid & 15;
    const uint4* E4 = (const uint4*)Ebf;
    for (int p4 = 0; p4 < 4; ++p4) {
        int nl = p4 * 16 + g;
        int v = b * 64 + nl;
        if (v >= NN) continue;
        float acc[8] = {};
        int i = off[nl], e1 = off[nl + 1];
        uint4 r[8];
        for (; i + 8 <= e1; i += 8) {
            #pragma unroll
            for (int k = 0; k < 8; ++k)
                r[k] = E4[(size_t)sorted[i + k] * 16 + c];
            __builtin_amdgcn_sched_barrier(0);
            #pragma unroll
            for (int k = 0; k < 8; ++k) addrow(acc, r[k]);
        }
        for (; i + 2 <= e1; i += 2) {
            uint4 r0 = E4[(size_t)sorted[i]     * 16 + c];
            uint4 r1 = E4[(size_t)sorted[i + 1] * 16 + c];
            addrow(acc, r0); addrow(acc, r1);
        }
        if (i < e1) addrow(acc, E4[(size_t)sorted[i] * 16 + c]);
        if (novf > 0) {
            for (int k = 0; k < novf; ++k) {
                int2 e = ovf[k];
                if (e.y == v) addrow(acc, E4[(size_t)e.x * 16 + c]);
            }
        }
        uint4 o;
        o.x = pack2(acc[0], acc[1]); o.y = pack2(acc[2], acc[3]);
        o.z = pack2(acc[4], acc[5]); o.w = pack2(acc[6], acc[7]);
        *(uint4*)&Hs[nl][c * 8] = o;
    }
    __syncthreads();

    const int wave = tid >> 6;
    const int lane = tid & 63;
    const int v0 = b * 64 + wave * 16;
    if (v0 >= NN) return;
    const int m = lane & 15;
    const int quad = lane >> 4;

    bf16x8 aH[4], aE[4];
    const unsigned short* hrow = &Hs[wave * 16 + m][quad * 8];
    const unsigned short* erow = Ebf + (size_t)(v0 + m) * DD + quad * 8;
    #pragma unroll
    for (int ks = 0; ks < 4; ++ks) {
        bf16x8 h8 = *(const bf16x8*)(hrow + ks * 32);
        bf16x8 e8 = *(const bf16x8*)(erow + ks * 32);
        aH[ks] = h8;
        bf16x8 eh;
        #pragma unroll
        for (int j = 0; j < 8; ++j)
            eh[j] = (short)rnebf(sbf(h8[j]) * sbf(e8[j]));
        aE[ks] = eh;
    }
    #pragma unroll
    for (int jt = 0; jt < 8; ++jt) {
        const int j0 = jt * 16;
        const unsigned short* w1r = W1b + (size_t)(j0 + m) * DD + quad * 8;
        const unsigned short* w2r = W2b + (size_t)(j0 + m) * DD + quad * 8;
        f32x4 acc1 = {0.f, 0.f, 0.f, 0.f}, acc2 = {0.f, 0.f, 0.f, 0.f};
        #pragma unroll
        for (int ks = 0; ks < 4; ++ks) {
            bf16x8 bw1 = *(const bf16x8*)(w1r + ks * 32);
            bf16x8 bw2 = *(const bf16x8*)(w2r + ks * 32);
            acc1 = __builtin_amdgcn_mfma_f32_16x16x32_bf16(aH[ks], bw1, acc1, 0, 0, 0);
            acc2 = __builtin_amdgcn_mfma_f32_16x16x32_bf16(aE[ks], bw2, acc2, 0, 0, 0);
        }
        const float bb1 = b1[j0 + m], bb2 = b2[j0 + m];
        #pragma unroll
        for (int i = 0; i < 4; ++i) {
            int row = v0 + quad * 4 + i;
            if (row < NN) {
                float x1 = acc1[i] + bb1; x1 = x1 > 0.f ? x1 : SLOPE * x1;
                float x2 = acc2[i] + bb2; x2 = x2 > 0.f ? x2 : SLOPE * x2;
                out[(size_t)row * DD + j0 + m] = x1 + x2;
            }
        }
    }
}

// ============== minimal fallback (ws too small): fp32 atomics ==============
__global__ __launch_bounds__(256) void scatter_add(
    const float* __restrict__ E, const int* __restrict__ src,
    const int* __restrict__ dst, float* __restrict__ H, int n_edges)
{
    int t = blockIdx.x * 256 + threadIdx.x;
    int e = t >> 5;
    if (e >= n_edges) return;
    int c = t & 31;
    float4 a = ((const float4*)E)[(size_t)src[e] * 32 + c];
    float* hp = H + (size_t)dst[e] * DD + c * 4;
    atomicAdd(hp + 0, a.x); atomicAdd(hp + 1, a.y);
    atomicAdd(hp + 2, a.z); atomicAdd(hp + 3, a.w);
}

__global__ __launch_bounds__(256) void fused_mlp(
    const float* __restrict__ E, const float* __restrict__ H,
    const float* __restrict__ W1, const float* __restrict__ b1,
    const float* __restrict__ W2, const float* __restrict__ b2,
    float* __restrict__ out)
{
    __shared__ float Hsf[32][DD];
    __shared__ float EHs[32][DD];
    __shared__ float W1s[DD][20];
    __shared__ float W2s[DD][20];
    const int tid = threadIdx.x;
    const int v0 = blockIdx.x * 32;
    const int nvalid = min(32, NN - v0);
    for (int i = 0; i < 4; ++i) {
        int f = tid + 256 * i;
        int n = f >> 5, c = f & 31;
        float4 h = make_float4(0.f, 0.f, 0.f, 0.f);
        float4 eh = h;
        if (n < nvalid) {
            h = ((const float4*)H)[(size_t)(v0 + n) * 32 + c];
            float4 e4 = ((const float4*)E)[(size_t)(v0 + n) * 32 + c];
            eh = make_float4(e4.x * h.x, e4.y * h.y, e4.z * h.z, e4.w * h.w);
        }
        *((float4*)&Hsf[n][c * 4]) = h;
        *((float4*)&EHs[n][c * 4]) = eh;
    }
    const int jg = tid & 63;
    const int n0 = (tid >> 6) * 8;
    float acc1a[8] = {}, acc1b[8] = {}, acc2a[8] = {}, acc2b[8] = {};
    for (int t8 = 0; t8 < 8; ++t8) {
        const int k0 = t8 * 16;
        __syncthreads();
        for (int i = 0; i < 8; ++i) {
            int f = tid + 256 * i;
            int j = f >> 4, kk = f & 15;
            W1s[j][kk] = W1[j * DD + k0 + kk];
            W2s[j][kk] = W2[j * DD + k0 + kk];
        }
        __syncthreads();
        for (int c = 0; c < 4; ++c) {
            float4 w1a = *((const float4*)&W1s[jg][c * 4]);
            float4 w1b = *((const float4*)&W1s[jg + 64][c * 4]);
            float4 w2a = *((const float4*)&W2s[jg][c * 4]);
            float4 w2b = *((const float4*)&W2s[jg + 64][c * 4]);
            const int kk = k0 + c * 4;
            for (int n = 0; n < 8; ++n) {
                float4 h = *((const float4*)&Hsf[n0 + n][kk]);
                float4 eh = *((const float4*)&EHs[n0 + n][kk]);
                acc1a[n] += h.x * w1a.x + h.y * w1a.y + h.z * w1a.z + h.w * w1a.w;
                acc1b[n] += h.x * w1b.x + h.y * w1b.y + h.z * w1b.z + h.w * w1b.w;
                acc2a[n] += eh.x * w2a.x + eh.y * w2a.y + eh.z * w2a.z + eh.w * w2a.w;
                acc2b[n] += eh.x * w2b.x + eh.y * w2b.y + eh.z * w2b.z + eh.w * w2b.w;
            }
        }
    }
    const float b1a = b1[jg], b1b = b1[jg + 64];
    const float b2a = b2[jg], b2b = b2[jg + 64];
    for (int n = 0; n < 8; ++n) {
        if (n0 + n < nvalid) {
            const int v = v0 + n0 + n;
            float x1 = acc1a[n] + b1a; x1 = x1 > 0.f ? x1 : SLOPE * x1;
            float x2 = acc2a[n] + b2a; x2 = x2 > 0.f ? x2 : SLOPE * x2;
            out[(size_t)v * DD + jg] = x1 + x2;
            float y1 = acc1b[n] + b1b; y1 = y1 > 0.f ? y1 : SLOPE * y1;
            float y2 = acc2b[n] + b2b; y2 = y2 > 0.f ? y2 : SLOPE * y2;
            out[(size_t)v * DD + jg + 64] = y1 + y2;
        }
    }
}
// ===========================================================================

extern "C" void kernel_launch(void* const* d_in, const int* in_sizes, int n_in,
                              void* d_out, int out_size, void* d_ws, size_t ws_size,
                              hipStream_t stream)
{
    const float* E  = (const float*)d_in[0];
    const float* W1 = (const float*)d_in[1];
    const float* b1 = (const float*)d_in[2];
    const float* W2 = (const float*)d_in[3];
    const float* b2 = (const float*)d_in[4];
    const int* src  = (const int*)d_in[5];
    const int* dst  = (const int*)d_in[6];
    float* out = (float*)d_out;
    const int n_edges = in_sizes[5];

    char* ws = (char*)d_ws;
    auto al = [](size_t x) { return (x + 255) & ~(size_t)255; };

    const int nch1 = (n_edges + ECH1 - 1) / ECH1;

    // counters: gtail1[NSB] | ovf_cnt[1] | gtail[NB]
    const size_t ctr_ints  = NSB + 1 + NB;
    const size_t off_ovf   = al(ctr_ints * 4);
    const size_t off_stag1 = al(off_ovf + (size_t)OVCAP * 8);
    const size_t off_stag  = al(off_stag1 + (size_t)NSB * SCAP * 4);
    const size_t off_Ebf   = al(off_stag + (size_t)NB * BCAP * 4);
    const size_t off_W1b   = al(off_Ebf + (size_t)NN * DD * 2);
    const size_t off_W2b   = al(off_W1b + (size_t)DD * DD * 2);
    const size_t need_bf   = off_W2b + (size_t)DD * DD * 2;     // ~27 MB
    const size_t off_Hf    = al(need_bf);
    const size_t need_split = off_Hf + (size_t)NN * DD * 4;     // ~53 MB

    if (ws_size >= need_bf) {
        int*  gtail1  = (int*)ws;
        int*  ovf_cnt = gtail1 + NSB;
        int*  gtail   = gtail1 + NSB + 1;
        int2* ovf     = (int2*)(ws + off_ovf);
        unsigned int*   stag1 = (unsigned int*)(ws + off_stag1);
        unsigned int*   stag  = (unsigned int*)(ws + off_stag);
        unsigned short* Ebf   = (unsigned short*)(ws + off_Ebf);
        unsigned short* W1b   = (unsigned short*)(ws + off_W1b);
        unsigned short* W2b   = (unsigned short*)(ws + off_W2b);

        const int NCV  = NN * DD / 8 + 2 * (DD * DD / 8);
        const int ncvb = (NCV + 511) / 512;

        hipMemsetAsync(ws, 0, ctr_ints * 4, stream);
        scatter_convert<<<nch1 + ncvb, 512, 0, stream>>>(
            E, W1, W2, src, dst, Ebf, W1b, W2b,
            gtail1, stag1, ovf_cnt, ovf, n_edges, nch1);
        rebin<<<NSB * RS, 256, 0, stream>>>(
            gtail1, stag1, gtail, stag, ovf_cnt, ovf);

        if (ws_size >= need_split) {
            float* Hf = (float*)(ws + off_Hf);
            bucket_gather<<<8 * GCHUNK, 256, 0, stream>>>(
                Ebf, gtail, stag, ovf_cnt, ovf, Hf);
            bucket_gemm<<<8 * GCHUNK, 256, 0, stream>>>(
                Hf, Ebf, W1b, W2b, b1, b2, out);
        } else {
            bucket_fused<<<NB, 256, 0, stream>>>(
                Ebf, gtail, stag, ovf_cnt, ovf, W1b, W2b, b1, b2, out);
        }
        return;
    }

    // fallback: fp32 atomics into H (= ws if it fits, else out), then fused MLP
    const size_t hbytes = (size_t)NN * DD * sizeof(float);
    float* H = (ws_size >= hbytes) ? (float*)ws : out;
    hipMemsetAsync(H, 0, hbytes, stream);
    scatter_add<<<((n_edges * 32) + 255) / 256, 256, 0, stream>>>(
        E, src, dst, H, n_edges);
    fused_mlp<<<(NN + 31) / 32, 256, 0, stream>>>(E, H, W1, b1, W2, b2, out);
}

// Round 12
// 203.238 us; speedup vs baseline: 1.0010x; 1.0010x over previous
//
#include <hip/hip_runtime.h>

#define NN 50000
#define DD 128
#define SLOPE 0.01f
#define NB 782        // buckets of 64 nodes: bucket = v>>6
#define BCAP 2304     // per-bucket cap; mean 2046, sigma 45 -> +5.7 sigma (+ovf net)
#define NSB 49        // super-buckets of 1024 nodes: sb = v>>10
#define SBW 1024
#define SCAP 34816    // per-super cap; mean 32768, sigma 179 -> +11 sigma
#define ECH1 4096     // edges per level-1 chunk (391 chunks)
#define RSL 2048      // records per rebin slice
#define RS 17         // slices per super (17*2048 = 34816 = SCAP)
#define OVCAP 8192
#define HP 136        // Hs row pitch (bf16) in the fused-fallback kernel
#define SROW0 24576   // src-half boundary: bands 0..5 vs 6..15 (rows >= 24576)

using bf16x8 = __attribute__((ext_vector_type(8))) short;
using f32x4  = __attribute__((ext_vector_type(4))) float;

// ---------------- bf16 helpers (RNE) ----------------
__device__ inline float bflo(unsigned int w) { return __uint_as_float(w << 16); }
__device__ inline float bfhi(unsigned int w) { return __uint_as_float(w & 0xffff0000u); }
__device__ inline float sbf(short s) {
    return __uint_as_float(((unsigned int)(unsigned short)s) << 16);
}
__device__ inline unsigned int rnebf(float f) {
    unsigned int u = __float_as_uint(f);
    return (u + 0x7fffu + ((u >> 16) & 1u)) >> 16;
}
__device__ inline unsigned int pack2(float lo, float hi) {
    return rnebf(lo) | (rnebf(hi) << 16);
}
__device__ inline void addrow(float* acc, uint4 r) {
    acc[0] += bflo(r.x); acc[1] += bfhi(r.x);
    acc[2] += bflo(r.y); acc[3] += bfhi(r.y);
    acc[4] += bflo(r.z); acc[5] += bfhi(r.z);
    acc[6] += bflo(r.w); acc[7] += bfhi(r.w);
}

// ROW-MAJOR Ebf (r6 lesson: column planes halve line efficiency).
__device__ inline void convert_item(
    const float* __restrict__ E, const float* __restrict__ W1,
    const float* __restrict__ W2, unsigned short* __restrict__ Ebf,
    unsigned short* __restrict__ W1b, unsigned short* __restrict__ W2b, int t)
{
    const int NE8 = NN * DD / 8;      // 800000
    const int NW8 = DD * DD / 8;      // 2048
    const float* s; unsigned short* d; int idx;
    if (t < NE8)                { s = E;  d = Ebf; idx = t; }
    else if (t < NE8 + NW8)     { s = W1; d = W1b; idx = t - NE8; }
    else if (t < NE8 + 2 * NW8) { s = W2; d = W2b; idx = t - NE8 - NW8; }
    else return;
    float4 a = ((const float4*)s)[(size_t)idx * 2];
    float4 b = ((const float4*)s)[(size_t)idx * 2 + 1];
    uint4 o;
    o.x = pack2(a.x, a.y); o.y = pack2(a.z, a.w);
    o.z = pack2(b.x, b.y); o.w = pack2(b.z, b.w);
    ((uint4*)d)[idx] = o;
}

// ---------------------------------------------------------------------------
// Level-1 binning + convert (r7 verbatim -- binning frozen).
// Record: u (bits 0..15) | v&1023 (bits 16..25).
// ---------------------------------------------------------------------------
__global__ __launch_bounds__(512) void scatter_convert(
    const float* __restrict__ E, const float* __restrict__ W1,
    const float* __restrict__ W2, const int* __restrict__ src,
    const int* __restrict__ dst, unsigned short* __restrict__ Ebf,
    unsigned short* __restrict__ W1b, unsigned short* __restrict__ W2b,
    int* __restrict__ gtail1, unsigned int* __restrict__ stag1,
    int* __restrict__ ovf_cnt, int2* __restrict__ ovf,
    int n_edges, int nch1)
{
    const int tid = threadIdx.x;
    if (blockIdx.x >= nch1) {
        convert_item(E, W1, W2, Ebf, W1b, W2b,
                     (blockIdx.x - nch1) * 512 + tid);
        return;
    }

    __shared__ int cnt49[NSB];
    const int e0 = blockIdx.x * ECH1;
    int vv[8], uu[8];

    if (tid < NSB) cnt49[tid] = 0;
    __syncthreads();
    #pragma unroll
    for (int k = 0; k < 8; ++k) {
        int idx = e0 + tid + k * 512;
        if (idx < n_edges) {
            vv[k] = dst[idx]; uu[k] = src[idx];
            atomicAdd(&cnt49[vv[k] >> 10], 1);
        } else vv[k] = -1;
    }
    __syncthreads();
    if (tid < NSB) {
        int c = cnt49[tid];
        cnt49[tid] = c ? atomicAdd(&gtail1[tid], c) : 0;  // -> running pos
    }
    __syncthreads();
    #pragma unroll
    for (int k = 0; k < 8; ++k) {
        if (vv[k] < 0) continue;
        int sb = vv[k] >> 10;
        int p = atomicAdd(&cnt49[sb], 1);
        if (p < SCAP) {
            stag1[(size_t)sb * SCAP + p] =
                (unsigned int)uu[k] | ((unsigned int)(vv[k] & 1023) << 16);
        } else {
            int oi = atomicAdd(ovf_cnt, 1);
            if (oi < OVCAP) ovf[oi] = make_int2(uu[k], vv[k]);
        }
    }
}

// ---------------------------------------------------------------------------
// Level-2 rebin (r7 verbatim).
// ---------------------------------------------------------------------------
__global__ __launch_bounds__(256) void rebin(
    const int* __restrict__ gtail1, const unsigned int* __restrict__ stag1,
    int* __restrict__ gtail, unsigned int* __restrict__ stag,
    int* __restrict__ ovf_cnt, int2* __restrict__ ovf)
{
    const int sb = blockIdx.x / RS, sl = blockIdx.x % RS;
    const int tid = threadIdx.x;
    int len = gtail1[sb]; len = len < SCAP ? len : SCAP;
    const int i0 = sl * RSL;
    const int i1 = min(i0 + RSL, len);

    __shared__ int cnt16[16], pos16[16];
    if (tid < 16) cnt16[tid] = 0;
    __syncthreads();

    unsigned int r[8];
    const unsigned int* seg = stag1 + (size_t)sb * SCAP;
    #pragma unroll
    for (int k = 0; k < 8; ++k) {
        int idx = i0 + tid + k * 256;
        if (idx < i1) {
            r[k] = seg[idx];
            atomicAdd(&cnt16[(r[k] >> 22) & 15], 1);
        } else r[k] = 0xffffffffu;
    }
    __syncthreads();
    if (tid < 16) {
        int c = cnt16[tid];
        int bb = sb * 16 + tid;
        pos16[tid] = (c && bb < NB) ? atomicAdd(&gtail[bb], c) : 0;
    }
    __syncthreads();
    #pragma unroll
    for (int k = 0; k < 8; ++k) {
        if (r[k] == 0xffffffffu) continue;
        int j = (r[k] >> 22) & 15;
        int p = atomicAdd(&pos16[j], 1);
        int bb = sb * 16 + j;
        if (p < BCAP) {
            stag[(size_t)bb * BCAP + p] = r[k] & 0x3fffffu;
        } else {
            int oi = atomicAdd(ovf_cnt, 1);
            if (oi < OVCAP)
                ovf[oi] = make_int2((int)(r[k] & 0xffffu),
                                    sb * SBW + (int)((r[k] >> 16) & 1023));
        }
    }
}

// ---------------------------------------------------------------------------
// bucket_gather.
// npart==1: EXACT r10 config (default dispatch, proven 43.6us / FETCH 90MB;
//   r11's sync-based XCD swizzle REGRESSED to 54us/142MB -- reverted).
// npart==2: FOOTPRINT-based XCD partition. Quadrant q=(srchalf s, colhalf h)
//   touches only a 3.2MB Ebf region (< 4MB per-XCD L2 -> zero capacity
//   misses once warm, robust to scheduling order). Quadrant q -> XCD pair
//   {2q,2q+1} via bid&7 (mechanism validated by r11's behavior shift).
//   Src-half partials go to Hf[s]; summed in bucket_gemm.
//   Sort is unchanged: bins = node<<4 | src>>12; half 0 = bins 0..5
//   (src<24576), half 1 = bins 6..15.
// ---------------------------------------------------------------------------
__global__ __launch_bounds__(256, 4) void bucket_gather(
    const unsigned short* __restrict__ Ebf, const int* __restrict__ gtail,
    const unsigned int* __restrict__ stag, const int* __restrict__ ovf_cnt,
    const int2* __restrict__ ovf, float* __restrict__ Hf, int npart)
{
    __shared__ unsigned short sorted[BCAP];   // 4.6 KB
    __shared__ int cnt1k[1024];               // counts -> placement pos
    __shared__ int bstart[1025];              // bin exclusive bases
    __shared__ int wsum[4];
    __shared__ int s_novf;

    int b, h, s;
    if (npart == 2) {
        const int xcd  = blockIdx.x & 7;
        const int slot = blockIdx.x >> 3;
        const int q    = xcd >> 1;            // quadrant 0..3
        h = q & 1; s = q >> 1;
        b = slot * 2 + (xcd & 1);
        if (b >= NB) return;
    } else {
        b = blockIdx.x >> 1; h = blockIdx.x & 1; s = 0;
    }
    const int tid = threadIdx.x;
    int len = gtail[b]; len = len < BCAP ? len : BCAP;
    const unsigned int* seg = stag + (size_t)b * BCAP;

    if (tid == 0) { int t = *ovf_cnt; s_novf = t < OVCAP ? t : OVCAP; }
    #pragma unroll
    for (int j = 0; j < 4; ++j) cnt1k[tid * 4 + j] = 0;
    __syncthreads();
    for (int i = tid; i < len; i += 256) {
        unsigned int r = seg[i];
        int key = (int)(((r >> 16) & 63) << 4) | (int)((r & 0xffffu) >> 12);
        atomicAdd(&cnt1k[key], 1);
    }
    __syncthreads();
    // exclusive scan of 1024 counters: 4 per thread + wave scan + wave bases
    {
        const int lane = tid & 63, w = tid >> 6;
        int c[4], loc[4]; int ss = 0;
        #pragma unroll
        for (int j = 0; j < 4; ++j) {
            c[j] = cnt1k[tid * 4 + j]; loc[j] = ss; ss += c[j];
        }
        int incl = ss;
        #pragma unroll
        for (int d = 1; d < 64; d <<= 1) {
            int t2 = __shfl_up(incl, d);
            if (lane >= d) incl += t2;
        }
        if (lane == 63) wsum[w] = incl;
        __syncthreads();
        int wbase = 0;
        for (int w2 = 0; w2 < w; ++w2) wbase += wsum[w2];
        int base = wbase + incl - ss;
        #pragma unroll
        for (int j = 0; j < 4; ++j) {
            bstart[tid * 4 + j] = base + loc[j];
            cnt1k[tid * 4 + j]  = base + loc[j];   // becomes pos
        }
        if (tid == 255) bstart[1024] = base + ss;  // == len
    }
    __syncthreads();
    for (int i = tid; i < len; i += 256) {
        unsigned int r = seg[i];
        int key = (int)(((r >> 16) & 63) << 4) | (int)((r & 0xffffu) >> 12);
        int p = atomicAdd(&cnt1k[key], 1);
        sorted[p] = (unsigned short)(r & 0xffffu);
    }
    __syncthreads();
    const int novf = s_novf;

    float* Hq = Hf + (size_t)s * NN * DD;

    // ---- gather: 8 lanes per node (one 128B line), 32 nodes/pass, 2 passes
    const int g = tid >> 3;
    const int c = tid & 7;
    const uint4* E4 = (const uint4*)Ebf;
    for (int p2 = 0; p2 < 2; ++p2) {
        int nl = p2 * 32 + g;
        int v = b * 64 + nl;
        if (v >= NN) continue;
        float acc[8] = {};
        int lo = nl * 16, hi = nl * 16 + 16;
        if (npart == 2) { if (s == 0) hi = nl * 16 + 6; else lo = nl * 16 + 6; }
        int i = bstart[lo], e1 = bstart[hi];
        uint4 r[8];
        for (; i + 8 <= e1; i += 8) {
            #pragma unroll
            for (int k = 0; k < 8; ++k)
                r[k] = E4[(size_t)sorted[i + k] * 16 + h * 8 + c];
            __builtin_amdgcn_sched_barrier(0);
            #pragma unroll
            for (int k = 0; k < 8; ++k) addrow(acc, r[k]);
        }
        for (; i + 2 <= e1; i += 2) {
            uint4 r0 = E4[(size_t)sorted[i]     * 16 + h * 8 + c];
            uint4 r1 = E4[(size_t)sorted[i + 1] * 16 + h * 8 + c];
            addrow(acc, r0); addrow(acc, r1);
        }
        if (i < e1) addrow(acc, E4[(size_t)sorted[i] * 16 + h * 8 + c]);

        if (novf > 0) {                    // rare path: fold overflow edges
            for (int k = 0; k < novf; ++k) {
                int2 e = ovf[k];
                if (e.y != v) continue;
                if (npart == 2 && ((e.x >= SROW0) ? 1 : 0) != s) continue;
                addrow(acc, E4[(size_t)e.x * 16 + h * 8 + c]);
            }
        }
        float* o = Hq + (size_t)v * DD + h * 64 + c * 8;
        *(float4*)o       = make_float4(acc[0], acc[1], acc[2], acc[3]);
        *(float4*)(o + 4) = make_float4(acc[4], acc[5], acc[6], acc[7]);
    }
}

// ---------------------------------------------------------------------------
// bucket_gemm (r8/r10 proven full-row config): grid NB; wave w -> rows
// w*16..+15. Sums npart fp32 Hf partials (rounds to bf16 once), MFMA+leaky.
// ---------------------------------------------------------------------------
__global__ __launch_bounds__(256) void bucket_gemm(
    const float* __restrict__ Hf, const unsigned short* __restrict__ Ebf,
    const unsigned short* __restrict__ W1b, const unsigned short* __restrict__ W2b,
    const float* __restrict__ b1, const float* __restrict__ b2,
    float* __restrict__ out, int npart)
{
    const int b = blockIdx.x;
    const int tid = threadIdx.x;
    const int wave = tid >> 6;
    const int lane = tid & 63;
    const int v0 = b * 64 + wave * 16;
    if (v0 >= NN) return;
    const int m = lane & 15;
    const int quad = lane >> 4;

    bf16x8 aH[4], aE[4];
    const float* hrow  = Hf + (size_t)(v0 + m) * DD + quad * 8;
    const float* hrow2 = hrow + (size_t)NN * DD;
    const unsigned short* erow = Ebf + (size_t)(v0 + m) * DD + quad * 8;
    #pragma unroll
    for (int ks = 0; ks < 4; ++ks) {
        float4 f0 = *(const float4*)(hrow + ks * 32);
        float4 f1 = *(const float4*)(hrow + ks * 32 + 4);
        if (npart == 2) {
            float4 g0 = *(const float4*)(hrow2 + ks * 32);
            float4 g1 = *(const float4*)(hrow2 + ks * 32 + 4);
            f0.x += g0.x; f0.y += g0.y; f0.z += g0.z; f0.w += g0.w;
            f1.x += g1.x; f1.y += g1.y; f1.z += g1.z; f1.w += g1.w;
        }
        bf16x8 e8 = *(const bf16x8*)(erow + ks * 32);
        bf16x8 h8, eh;
        h8[0] = (short)rnebf(f0.x); h8[1] = (short)rnebf(f0.y);
        h8[2] = (short)rnebf(f0.z); h8[3] = (short)rnebf(f0.w);
        h8[4] = (short)rnebf(f1.x); h8[5] = (short)rnebf(f1.y);
        h8[6] = (short)rnebf(f1.z); h8[7] = (short)rnebf(f1.w);
        #pragma unroll
        for (int j = 0; j < 8; ++j)
            eh[j] = (short)rnebf(sbf(h8[j]) * sbf(e8[j]));
        aH[ks] = h8; aE[ks] = eh;
    }

    #pragma unroll
    for (int jt = 0; jt < 8; ++jt) {
        const int j0 = jt * 16;
        const unsigned short* w1r = W1b + (size_t)(j0 + m) * DD + quad * 8;
        const unsigned short* w2r = W2b + (size_t)(j0 + m) * DD + quad * 8;
        f32x4 acc1 = {0.f, 0.f, 0.f, 0.f}, acc2 = {0.f, 0.f, 0.f, 0.f};
        #pragma unroll
        for (int ks = 0; ks < 4; ++ks) {
            bf16x8 bw1 = *(const bf16x8*)(w1r + ks * 32);
            bf16x8 bw2 = *(const bf16x8*)(w2r + ks * 32);
            acc1 = __builtin_amdgcn_mfma_f32_16x16x32_bf16(aH[ks], bw1, acc1, 0, 0, 0);
            acc2 = __builtin_amdgcn_mfma_f32_16x16x32_bf16(aE[ks], bw2, acc2, 0, 0, 0);
        }
        const float bb1 = b1[j0 + m], bb2 = b2[j0 + m];
        #pragma unroll
        for (int i = 0; i < 4; ++i) {
            int row = v0 + quad * 4 + i;
            if (row < NN) {
                float x1 = acc1[i] + bb1; x1 = x1 > 0.f ? x1 : SLOPE * x1;
                float x2 = acc2[i] + bb2; x2 = x2 > 0.f ? x2 : SLOPE * x2;
                out[(size_t)row * DD + j0 + m] = x1 + x2;
            }
        }
    }
}

// ---------------------------------------------------------------------------
// Fused fallback (r7 verbatim, used when ws can't hold Hf): 84-85 us proven.
// ---------------------------------------------------------------------------
__global__ __launch_bounds__(256, 4) void bucket_fused(
    const unsigned short* __restrict__ Ebf, const int* __restrict__ gtail,
    const unsigned int* __restrict__ stag, const int* __restrict__ ovf_cnt,
    const int2* __restrict__ ovf,
    const unsigned short* __restrict__ W1b, const unsigned short* __restrict__ W2b,
    const float* __restrict__ b1, const float* __restrict__ b2,
    float* __restrict__ out)
{
    __shared__ unsigned short sorted[BCAP];
    __shared__ unsigned short Hs[64][HP];
    __shared__ int cnt[64], off[65], pos[64];
    __shared__ int s_novf;

    const int b = blockIdx.x;
    const int tid = threadIdx.x;
    int len = gtail[b]; len = len < BCAP ? len : BCAP;
    const unsigned int* seg = stag + (size_t)b * BCAP;

    if (tid == 0) { int t = *ovf_cnt; s_novf = t < OVCAP ? t : OVCAP; }
    if (tid < 64) cnt[tid] = 0;
    __syncthreads();
    for (int i = tid; i < len; i += 256)
        atomicAdd(&cnt[(seg[i] >> 16) & 63], 1);
    __syncthreads();
    if (tid < 64) {
        int cv = cnt[tid];
        int incl = cv;
        #pragma unroll
        for (int d = 1; d < 64; d <<= 1) {
            int t2 = __shfl_up(incl, d);
            if (tid >= d) incl += t2;
        }
        off[tid] = incl - cv;
        pos[tid] = incl - cv;
        if (tid == 63) off[64] = incl;
    }
    __syncthreads();
    for (int i = tid; i < len; i += 256) {
        unsigned int r = seg[i];
        int p = atomicAdd(&pos[(r >> 16) & 63], 1);
        sorted[p] = (unsigned short)(r & 0xffffu);
    }
    __syncthreads();
    const int novf = s_novf;

    const int g = tid >> 4;
    const int c = tid & 15;
    const uint4* E4 = (const uint4*)Ebf;
    for (int p4 = 0; p4 < 4; ++p4) {
        int nl = p4 * 16 + g;
        int v = b * 64 + nl;
        if (v >= NN) continue;
        float acc[8] = {};
        int i = off[nl], e1 = off[nl + 1];
        uint4 r[8];
        for (; i + 8 <= e1; i += 8) {
            #pragma unroll
            for (int k = 0; k < 8; ++k)
                r[k] = E4[(size_t)sorted[i + k] * 16 + c];
            __builtin_amdgcn_sched_barrier(0);
            #pragma unroll
            for (int k = 0; k < 8; ++k) addrow(acc, r[k]);
        }
        for (; i + 2 <= e1; i += 2) {
            uint4 r0 = E4[(size_t)sorted[i]     * 16 + c];
            uint4 r1 = E4[(size_t)sorted[i + 1] * 16 + c];
            addrow(acc, r0); addrow(acc, r1);
        }
        if (i < e1) addrow(acc, E4[(size_t)sorted[i] * 16 + c]);
        if (novf > 0) {
            for (int k = 0; k < novf; ++k) {
                int2 e = ovf[k];
                if (e.y == v) addrow(acc, E4[(size_t)e.x * 16 + c]);
            }
        }
        uint4 o;
        o.x = pack2(acc[0], acc[1]); o.y = pack2(acc[2], acc[3]);
        o.z = pack2(acc[4], acc[5]); o.w = pack2(acc[6], acc[7]);
        *(uint4*)&Hs[nl][c * 8] = o;
    }
    __syncthreads();

    const int wave = tid >> 6;
    const int lane = tid & 63;
    const int v0 = b * 64 + wave * 16;
    if (v0 >= NN) return;
    const int m = lane & 15;
    const int quad = lane >> 4;

    bf16x8 aH[4], aE[4];
    const unsigned short* hrow = &Hs[wave * 16 + m][quad * 8];
    const unsigned short* erow = Ebf + (size_t)(v0 + m) * DD + quad * 8;
    #pragma unroll
    for (int ks = 0; ks < 4; ++ks) {
        bf16x8 h8 = *(const bf16x8*)(hrow + ks * 32);
        bf16x8 e8 = *(const bf16x8*)(erow + ks * 32);
        aH[ks] = h8;
        bf16x8 eh;
        #pragma unroll
        for (int j = 0; j < 8; ++j)
            eh[j] = (short)rnebf(sbf(h8[j]) * sbf(e8[j]));
        aE[ks] = eh;
    }
    #pragma unroll
    for (int jt = 0; jt < 8; ++jt) {
        const int j0 = jt * 16;
        const unsigned short* w1r = W1b + (size_t)(j0 + m) * DD + quad * 8;
        const unsigned short* w2r = W2b + (size_t)(j0 + m) * DD + quad * 8;
        f32x4 acc1 = {0.f, 0.f, 0.f, 0.f}, acc2 = {0.f, 0.f, 0.f, 0.f};
        #pragma unroll
        for (int ks = 0; ks < 4; ++ks) {
            bf16x8 bw1 = *(const bf16x8*)(w1r + ks * 32);
            bf16x8 bw2 = *(const bf16x8*)(w2r + ks * 32);
            acc1 = __builtin_amdgcn_mfma_f32_16x16x32_bf16(aH[ks], bw1, acc1, 0, 0, 0);
            acc2 = __builtin_amdgcn_mfma_f32_16x16x32_bf16(aE[ks], bw2, acc2, 0, 0, 0);
        }
        const float bb1 = b1[j0 + m], bb2 = b2[j0 + m];
        #pragma unroll
        for (int i = 0; i < 4; ++i) {
            int row = v0 + quad * 4 + i;
            if (row < NN) {
                float x1 = acc1[i] + bb1; x1 = x1 > 0.f ? x1 : SLOPE * x1;
                float x2 = acc2[i] + bb2; x2 = x2 > 0.f ? x2 : SLOPE * x2;
                out[(size_t)row * DD + j0 + m] = x1 + x2;
            }
        }
    }
}

// ============== minimal fallback (ws too small): fp32 atomics ==============
__global__ __launch_bounds__(256) void scatter_add(
    const float* __restrict__ E, const int* __restrict__ src,
    const int* __restrict__ dst, float* __restrict__ H, int n_edges)
{
    int t = blockIdx.x * 256 + threadIdx.x;
    int e = t >> 5;
    if (e >= n_edges) return;
    int c = t & 31;
    float4 a = ((const float4*)E)[(size_t)src[e] * 32 + c];
    float* hp = H + (size_t)dst[e] * DD + c * 4;
    atomicAdd(hp + 0, a.x); atomicAdd(hp + 1, a.y);
    atomicAdd(hp + 2, a.z); atomicAdd(hp + 3, a.w);
}

__global__ __launch_bounds__(256) void fused_mlp(
    const float* __restrict__ E, const float* __restrict__ H,
    const float* __restrict__ W1, const float* __restrict__ b1,
    const float* __restrict__ W2, const float* __restrict__ b2,
    float* __restrict__ out)
{
    __shared__ float Hsf[32][DD];
    __shared__ float EHs[32][DD];
    __shared__ float W1s[DD][20];
    __shared__ float W2s[DD][20];
    const int tid = threadIdx.x;
    const int v0 = blockIdx.x * 32;
    const int nvalid = min(32, NN - v0);
    for (int i = 0; i < 4; ++i) {
        int f = tid + 256 * i;
        int n = f >> 5, c = f & 31;
        float4 h = make_float4(0.f, 0.f, 0.f, 0.f);
        float4 eh = h;
        if (n < nvalid) {
            h = ((const float4*)H)[(size_t)(v0 + n) * 32 + c];
            float4 e4 = ((const float4*)E)[(size_t)(v0 + n) * 32 + c];
            eh = make_float4(e4.x * h.x, e4.y * h.y, e4.z * h.z, e4.w * h.w);
        }
        *((float4*)&Hsf[n][c * 4]) = h;
        *((float4*)&EHs[n][c * 4]) = eh;
    }
    const int jg = tid & 63;
    const int n0 = (tid >> 6) * 8;
    float acc1a[8] = {}, acc1b[8] = {}, acc2a[8] = {}, acc2b[8] = {};
    for (int t8 = 0; t8 < 8; ++t8) {
        const int k0 = t8 * 16;
        __syncthreads();
        for (int i = 0; i < 8; ++i) {
            int f = tid + 256 * i;
            int j = f >> 4, kk = f & 15;
            W1s[j][kk] = W1[j * DD + k0 + kk];
            W2s[j][kk] = W2[j * DD + k0 + kk];
        }
        __syncthreads();
        for (int c = 0; c < 4; ++c) {
            float4 w1a = *((const float4*)&W1s[jg][c * 4]);
            float4 w1b = *((const float4*)&W1s[jg + 64][c * 4]);
            float4 w2a = *((const float4*)&W2s[jg][c * 4]);
            float4 w2b = *((const float4*)&W2s[jg + 64][c * 4]);
            const int kk = k0 + c * 4;
            for (int n = 0; n < 8; ++n) {
                float4 h = *((const float4*)&Hsf[n0 + n][kk]);
                float4 eh = *((const float4*)&EHs[n0 + n][kk]);
                acc1a[n] += h.x * w1a.x + h.y * w1a.y + h.z * w1a.z + h.w * w1a.w;
                acc1b[n] += h.x * w1b.x + h.y * w1b.y + h.z * w1b.z + h.w * w1b.w;
                acc2a[n] += eh.x * w2a.x + eh.y * w2a.y + eh.z * w2a.z + eh.w * w2a.w;
                acc2b[n] += eh.x * w2b.x + eh.y * w2b.y + eh.z * w2b.z + eh.w * w2b.w;
            }
        }
    }
    const float b1a = b1[jg], b1b = b1[jg + 64];
    const float b2a = b2[jg], b2b = b2[jg + 64];
    for (int n = 0; n < 8; ++n) {
        if (n0 + n < nvalid) {
            const int v = v0 + n0 + n;
            float x1 = acc1a[n] + b1a; x1 = x1 > 0.f ? x1 : SLOPE * x1;
            float x2 = acc2a[n] + b2a; x2 = x2 > 0.f ? x2 : SLOPE * x2;
            out[(size_t)v * DD + jg] = x1 + x2;
            float y1 = acc1b[n] + b1b; y1 = y1 > 0.f ? y1 : SLOPE * y1;
            float y2 = acc2b[n] + b2b; y2 = y2 > 0.f ? y2 : SLOPE * y2;
            out[(size_t)v * DD + jg + 64] = y1 + y2;
        }
    }
}
// ===========================================================================

extern "C" void kernel_launch(void* const* d_in, const int* in_sizes, int n_in,
                              void* d_out, int out_size, void* d_ws, size_t ws_size,
                              hipStream_t stream)
{
    const float* E  = (const float*)d_in[0];
    const float* W1 = (const float*)d_in[1];
    const float* b1 = (const float*)d_in[2];
    const float* W2 = (const float*)d_in[3];
    const float* b2 = (const float*)d_in[4];
    const int* src  = (const int*)d_in[5];
    const int* dst  = (const int*)d_in[6];
    float* out = (float*)d_out;
    const int n_edges = in_sizes[5];

    char* ws = (char*)d_ws;
    auto al = [](size_t x) { return (x + 255) & ~(size_t)255; };

    const int nch1 = (n_edges + ECH1 - 1) / ECH1;

    // counters: gtail1[NSB] | ovf_cnt[1] | gtail[NB]
    const size_t ctr_ints  = NSB + 1 + NB;
    const size_t off_ovf   = al(ctr_ints * 4);
    const size_t off_stag1 = al(off_ovf + (size_t)OVCAP * 8);
    const size_t off_stag  = al(off_stag1 + (size_t)NSB * SCAP * 4);
    const size_t off_Ebf   = al(off_stag + (size_t)NB * BCAP * 4);
    const size_t off_W1b   = al(off_Ebf + (size_t)NN * DD * 2);
    const size_t off_W2b   = al(off_W1b + (size_t)DD * DD * 2);
    const size_t need_bf   = off_W2b + (size_t)DD * DD * 2;     // ~27 MB
    const size_t off_Hf    = al(need_bf);
    const size_t need_sp1  = off_Hf + (size_t)NN * DD * 4;      // ~53 MB
    const size_t need_sp2  = off_Hf + (size_t)NN * DD * 8;      // ~78.6 MB

    if (ws_size >= need_bf) {
        int*  gtail1  = (int*)ws;
        int*  ovf_cnt = gtail1 + NSB;
        int*  gtail   = gtail1 + NSB + 1;
        int2* ovf     = (int2*)(ws + off_ovf);
        unsigned int*   stag1 = (unsigned int*)(ws + off_stag1);
        unsigned int*   stag  = (unsigned int*)(ws + off_stag);
        unsigned short* Ebf   = (unsigned short*)(ws + off_Ebf);
        unsigned short* W1b   = (unsigned short*)(ws + off_W1b);
        unsigned short* W2b   = (unsigned short*)(ws + off_W2b);

        const int NCV  = NN * DD / 8 + 2 * (DD * DD / 8);
        const int ncvb = (NCV + 511) / 512;

        hipMemsetAsync(ws, 0, ctr_ints * 4, stream);
        scatter_convert<<<nch1 + ncvb, 512, 0, stream>>>(
            E, W1, W2, src, dst, Ebf, W1b, W2b,
            gtail1, stag1, ovf_cnt, ovf, n_edges, nch1);
        rebin<<<NSB * RS, 256, 0, stream>>>(
            gtail1, stag1, gtail, stag, ovf_cnt, ovf);

        if (ws_size >= need_sp1) {
            float* Hf = (float*)(ws + off_Hf);
            const int npart = (ws_size >= need_sp2) ? 2 : 1;
            const int ggrid = (npart == 2) ? 8 * 392 : NB * 2;
            bucket_gather<<<ggrid, 256, 0, stream>>>(
                Ebf, gtail, stag, ovf_cnt, ovf, Hf, npart);
            bucket_gemm<<<NB, 256, 0, stream>>>(
                Hf, Ebf, W1b, W2b, b1, b2, out, npart);
        } else {
            bucket_fused<<<NB, 256, 0, stream>>>(
                Ebf, gtail, stag, ovf_cnt, ovf, W1b, W2b, b1, b2, out);
        }
        return;
    }

    // fallback: fp32 atomics into H (= ws if it fits, else out), then fused MLP
    const size_t hbytes = (size_t)NN * DD * sizeof(float);
    float* H = (ws_size >= hbytes) ? (float*)ws : out;
    hipMemsetAsync(H, 0, hbytes, stream);
    scatter_add<<<((n_edges * 32) + 255) / 256, 256, 0, stream>>>(
        E, src, dst, H, n_edges);
    fused_mlp<<<(NN + 31) / 32, 256, 0, stream>>>(E, H, W1, b1, W2, b2, out);
}